// Round 1
// baseline (125.865 us; speedup 1.0000x reference)
//
#include <hip/hip_runtime.h>

#define JITTER 1e-5f

// ---------------------------------------------------------------------------
// Kernel 1: build Kzz (64x64 RBF + jitter) and invert via Gauss-Jordan.
// Single block, 256 threads. Kzz ~ I + small E (random 8-D points, ls=1)
// -> no pivoting needed. Writes 64x64 f32 inverse to ws.
// ---------------------------------------------------------------------------
__global__ __launch_bounds__(256) void kzz_invert_kernel(
    const float* __restrict__ inducing,  // (64,8)
    const float* __restrict__ pvar,
    const float* __restrict__ pls,
    float* __restrict__ inv_out)         // (64,64)
{
    const int tid = threadIdx.x;
    __shared__ float Z[64 * 8];
    __shared__ float M[64 * 129];        // augmented [Kzz | I], pitch 129

    for (int i = tid; i < 512; i += 256) Z[i] = inducing[i];
    __syncthreads();

    const float var = pvar[0];
    const float ls  = pls[0];
    const float sc  = 0.5f / (ls * ls);

    for (int e = tid; e < 4096; e += 256) {
        const int i = e >> 6, j = e & 63;
        float sq = 0.f;
#pragma unroll
        for (int d = 0; d < 8; ++d) {
            const float df = Z[i * 8 + d] - Z[j * 8 + d];
            sq += df * df;
        }
        float v = var * expf(-sq * sc);
        if (i == j) v += JITTER * var;
        M[i * 129 + j]      = v;
        M[i * 129 + 64 + j] = (i == j) ? 1.f : 0.f;
    }
    __syncthreads();

    const int r  = tid >> 2;          // row 0..63 (4 threads/row)
    const int c0 = (tid & 3) * 32;    // column quarter of the 128-wide row

    for (int k = 0; k < 64; ++k) {
        const float rinv = 1.0f / M[k * 129 + k];   // all read pre-scale pivot
        __syncthreads();
        if (tid < 128) M[k * 129 + tid] *= rinv;    // scale pivot row
        __syncthreads();
        const float f = M[r * 129 + k];             // read multipliers
        __syncthreads();
        if (r != k) {
#pragma unroll 8
            for (int c = c0; c < c0 + 32; ++c)
                M[r * 129 + c] -= f * M[k * 129 + c];
        }
        __syncthreads();
    }

    for (int e = tid; e < 4096; e += 256) {
        const int i = e >> 6, j = e & 63;
        inv_out[e] = M[i * 129 + 64 + j];
    }
}

// ---------------------------------------------------------------------------
// Kernel 2: one block per particle n (512 blocks x 256 threads).
//   kfz = rbf(x_n, Z);  a = Kzz^-1 kfz;  B = var - <kfz,a>
//   t[j]  = sum_mm a[mm]^2 * gamma[n, j*64+mm]
//   c[i]  = B*K[i,i] + nv ;  d[i] = sum_j K[i,j]^2 t[j] + c[i]
//   s1[j] = sum_i K[i,j]   * y[i]/c[i]
//   s2[j] = sum_i K[i,j]^2 / d[i]
//   g[k]     = ga - (ga*a[mm])^2 * s2[j]              (k = j*64+mm)
//   m_new[k] = g * ( z/ga + a[mm]*s1[j] )
// ---------------------------------------------------------------------------
__global__ __launch_bounds__(256) void diag_sgp_kernel(
    const float* __restrict__ x,        // (n,8)
    const float* __restrict__ y,        // (n,32)
    const float* __restrict__ z,        // (n,2048)
    const float* __restrict__ gamma,    // (n,2048)
    const float* __restrict__ inducing, // (64,8)
    const float* __restrict__ Kmat,     // (32,32)
    const float* __restrict__ pvar,
    const float* __restrict__ pls,
    const float* __restrict__ pnoise,
    const float* __restrict__ kinv,     // (64,64)
    float* __restrict__ out,            // [m_new (n,2048) | g (n,2048)]
    int n_total)
{
    const int n   = blockIdx.x;
    const int tid = threadIdx.x;

    __shared__ float Kl[1024];
    __shared__ float xl[8], yl[32];
    __shared__ float kfz[64], a_sh[64];
    __shared__ float t_sh[32], rc[32], rd[32], s1[32], s2[32];
    __shared__ float part[256];
    __shared__ float Bsh;

    for (int i = tid; i < 1024; i += 256) Kl[i] = Kmat[i];
    if (tid < 8)  xl[tid] = x[n * 8 + tid];
    if (tid < 32) yl[tid] = y[n * 32 + tid];
    const float var = pvar[0], ls = pls[0], nv = pnoise[0];
    __syncthreads();

    const float sc = 0.5f / (ls * ls);
    if (tid < 64) {
        float sq = 0.f;
#pragma unroll
        for (int d = 0; d < 8; ++d) {
            const float df = xl[d] - inducing[tid * 8 + d];
            sq += df * df;
        }
        kfz[tid] = var * expf(-sq * sc);
    }
    __syncthreads();

    if (tid < 64) {               // a = Kzz^-1 * kfz (symmetric: use columns)
        float acc = 0.f;
        for (int j = 0; j < 64; ++j) acc += kinv[j * 64 + tid] * kfz[j];
        a_sh[tid] = acc;
    }
    __syncthreads();

    if (tid < 64) {               // wave 0: B = var - <kfz, a>
        float v = kfz[tid] * a_sh[tid];
        for (int off = 32; off; off >>= 1) v += __shfl_down(v, off);
        if (tid == 0) Bsh = var - v;
    }

    // gamma load + per-thread partial of t[j]
    const int   k8   = tid * 8;
    const int   jrow = tid >> 3;          // j = k/64, constant per thread
    const float4 g0 = *reinterpret_cast<const float4*>(gamma + (size_t)n * 2048 + k8);
    const float4 g1 = *reinterpret_cast<const float4*>(gamma + (size_t)n * 2048 + k8 + 4);
    float ga[8] = {g0.x, g0.y, g0.z, g0.w, g1.x, g1.y, g1.z, g1.w};

    float as[8];
    const int ab = (tid & 7) * 8;         // mm = (tid&7)*8 + e
#pragma unroll
    for (int e = 0; e < 8; ++e) as[e] = a_sh[ab + e];

    float pt = 0.f;
#pragma unroll
    for (int e = 0; e < 8; ++e) pt += as[e] * as[e] * ga[e];
    part[tid] = pt;
    __syncthreads();

    if (tid < 32) {
        float s = 0.f;
#pragma unroll
        for (int u = 0; u < 8; ++u) s += part[tid * 8 + u];
        t_sh[tid] = s;
    }
    __syncthreads();

    if (tid < 32) {                        // d, c per output dim i
        float acc = 0.f;
        for (int jj = 0; jj < 32; ++jj) {
            const float kv = Kl[tid * 32 + jj];
            acc += kv * kv * t_sh[jj];
        }
        const float ci = Bsh * Kl[tid * 33] + nv;
        const float di = acc + ci;
        rc[tid] = yl[tid] / ci;
        rd[tid] = 1.0f / di;
    }
    __syncthreads();

    if (tid < 32) {                        // s1, s2 per j
        float sa = 0.f, sb = 0.f;
        for (int i = 0; i < 32; ++i) {
            const float kv = Kl[i * 32 + tid];
            sa += kv * rc[i];
            sb += kv * kv * rd[i];
        }
        s1[tid] = sa;
        s2[tid] = sb;
    }
    __syncthreads();

    const float4 z0 = *reinterpret_cast<const float4*>(z + (size_t)n * 2048 + k8);
    const float4 z1 = *reinterpret_cast<const float4*>(z + (size_t)n * 2048 + k8 + 4);
    const float zv[8] = {z0.x, z0.y, z0.z, z0.w, z1.x, z1.y, z1.z, z1.w};

    const float s1j = s1[jrow], s2j = s2[jrow];
    float mn[8], gg[8];
#pragma unroll
    for (int e = 0; e < 8; ++e) {
        const float ge = ga[e];
        const float am = as[e];
        const float gm = ge * am;
        const float gv = ge - gm * gm * s2j;
        gg[e] = gv;
        mn[e] = gv * (zv[e] / ge + am * s1j);
    }

    float* o_m = out + (size_t)n * 2048 + k8;
    float* o_g = out + (size_t)n_total * 2048 + (size_t)n * 2048 + k8;
    *reinterpret_cast<float4*>(o_m)     = make_float4(mn[0], mn[1], mn[2], mn[3]);
    *reinterpret_cast<float4*>(o_m + 4) = make_float4(mn[4], mn[5], mn[6], mn[7]);
    *reinterpret_cast<float4*>(o_g)     = make_float4(gg[0], gg[1], gg[2], gg[3]);
    *reinterpret_cast<float4*>(o_g + 4) = make_float4(gg[4], gg[5], gg[6], gg[7]);
}

extern "C" void kernel_launch(void* const* d_in, const int* in_sizes, int n_in,
                              void* d_out, int out_size, void* d_ws, size_t ws_size,
                              hipStream_t stream)
{
    const float* x        = (const float*)d_in[0];
    const float* y        = (const float*)d_in[1];
    const float* z        = (const float*)d_in[2];
    const float* gamma    = (const float*)d_in[3];
    const float* inducing = (const float*)d_in[4];
    const float* Kmat     = (const float*)d_in[5];
    const float* pvar     = (const float*)d_in[6];
    const float* pls      = (const float*)d_in[7];
    const float* pnoise   = (const float*)d_in[8];
    float* out  = (float*)d_out;
    float* kinv = (float*)d_ws;          // 64*64*4 = 16 KB scratch

    const int n = in_sizes[0] / 8;       // 512

    kzz_invert_kernel<<<dim3(1), dim3(256), 0, stream>>>(inducing, pvar, pls, kinv);
    diag_sgp_kernel<<<dim3(n), dim3(256), 0, stream>>>(
        x, y, z, gamma, inducing, Kmat, pvar, pls, pnoise, kinv, out, n);
}

// Round 3
// 48.660 us; speedup vs baseline: 2.5866x; 2.5866x over previous
//
#include <hip/hip_runtime.h>

#define JITTER 1e-5f

// ---------------------------------------------------------------------------
// Kernel 1: register-resident Gauss-Jordan inversion of Kzz/var (64x64).
// 1024 threads = 16 waves. Thread (r = tid&63, q = tid>>6) owns columns
// q*8..q*8+7 of row r of the augmented [Kzz | I] in 8 VGPRs. The 64-step
// pivot loop is fully unrolled so every register index is compile-time.
// Per step: 2 barriers; all LDS reads are broadcasts (free) or 2-way
// aliased (free). Double-buffered row/col staging kills WAR hazards.
// Unpivoted GJ is stable here: Kzz ~ I + small PSD perturbation (validated
// round 1: absmax 4.9e-4).
// ---------------------------------------------------------------------------
__global__ __launch_bounds__(1024) void kzz_invert_fast(
    const float* __restrict__ inducing,  // (64,8)
    const float* __restrict__ pls,
    float* __restrict__ inv_out)         // (64,64) = (Kzz/var)^-1
{
    const int tid = threadIdx.x;
    const int r = tid & 63;
    const int q = tid >> 6;              // 0..15 (cols q*8 .. q*8+7)

    __shared__ float Zt[8 * 64];                     // Zt[d][j]
    __shared__ __align__(16) float rowbuf[2][128];   // scaled pivot row
    __shared__ float colbuf[2][64];                  // pivot column (pre-update)

    if (tid < 512) Zt[(tid & 7) * 64 + (tid >> 3)] = inducing[tid];
    const float ls = pls[0];
    const float sc = 0.5f / (ls * ls);
    __syncthreads();

    // init: left half = Kzz/var = C + jitter*I, right half = I
    float a[8];
    if (q < 8) {
#pragma unroll
        for (int j = 0; j < 8; ++j) {
            const int c = q * 8 + j;
            float sq = 0.f;
#pragma unroll
            for (int d = 0; d < 8; ++d) {
                const float df = Zt[d * 64 + r] - Zt[d * 64 + c];
                sq += df * df;
            }
            a[j] = expf(-sq * sc) + ((r == c) ? JITTER : 0.f);
        }
    } else {
#pragma unroll
        for (int j = 0; j < 8; ++j)
            a[j] = ((q - 8) * 8 + j == r) ? 1.f : 0.f;
    }

#pragma unroll
    for (int k = 0; k < 64; ++k) {
        const int qk = k >> 3, jk = k & 7, buf = k & 1;
        // phase 1: publish pivot column (pre-update values of col k)
        if (q == qk) colbuf[buf][r] = a[jk];
        __syncthreads();
        // phase 2: row-k threads scale their slice and publish it
        const float rinv = 1.0f / colbuf[buf][k];     // broadcast read
        if (r == k) {
#pragma unroll
            for (int j = 0; j < 8; ++j) a[j] *= rinv;
            *reinterpret_cast<float4*>(&rowbuf[buf][q * 8])     =
                make_float4(a[0], a[1], a[2], a[3]);
            *reinterpret_cast<float4*>(&rowbuf[buf][q * 8 + 4]) =
                make_float4(a[4], a[5], a[6], a[7]);
        }
        __syncthreads();
        // phase 3: eliminate
        if (r != k) {
            const float f = colbuf[buf][r];           // 2-way alias (free)
            const float4 rv0 = *reinterpret_cast<const float4*>(&rowbuf[buf][q * 8]);
            const float4 rv1 = *reinterpret_cast<const float4*>(&rowbuf[buf][q * 8 + 4]);
            a[0] = fmaf(-f, rv0.x, a[0]);
            a[1] = fmaf(-f, rv0.y, a[1]);
            a[2] = fmaf(-f, rv0.z, a[2]);
            a[3] = fmaf(-f, rv0.w, a[3]);
            a[4] = fmaf(-f, rv1.x, a[4]);
            a[5] = fmaf(-f, rv1.y, a[5]);
            a[6] = fmaf(-f, rv1.z, a[6]);
            a[7] = fmaf(-f, rv1.w, a[7]);
        }
        // no 3rd barrier: next step writes the OTHER buffer; same buffer is
        // reused only at step k+2, with >=2 barriers in between.
    }

    if (q >= 8) {                         // right half now holds the inverse
        float* o = inv_out + r * 64 + (q - 8) * 8;
        *reinterpret_cast<float4*>(o)     = make_float4(a[0], a[1], a[2], a[3]);
        *reinterpret_cast<float4*>(o + 4) = make_float4(a[4], a[5], a[6], a[7]);
    }
}

// ---------------------------------------------------------------------------
// Kernel 2: one block per particle n (512 blocks x 256 threads).
// VERBATIM the round-1 passing kernel (absmax 4.9e-4).
//   kfz = rbf(x_n, Z);  a = Kzz^-1 kfz;  B = var - <kfz,a>
//   t[j]  = sum_mm a[mm]^2 * gamma[n, j*64+mm]
//   c[i]  = B*K[i,i] + nv ;  d[i] = sum_j K[i,j]^2 t[j] + c[i]
//   s1[j] = sum_i K[i,j]   * y[i]/c[i] ;  s2[j] = sum_i K[i,j]^2 / d[i]
//   g[k]     = ga - (ga*a[mm])^2 * s2[j]          (k = j*64+mm)
//   m_new[k] = g * ( z/ga + a[mm]*s1[j] )
// ---------------------------------------------------------------------------
__global__ __launch_bounds__(256) void diag_sgp_kernel(
    const float* __restrict__ x,        // (n,8)
    const float* __restrict__ y,        // (n,32)
    const float* __restrict__ z,        // (n,2048)
    const float* __restrict__ gamma,    // (n,2048)
    const float* __restrict__ inducing, // (64,8)
    const float* __restrict__ Kmat,     // (32,32)
    const float* __restrict__ pvar,
    const float* __restrict__ pls,
    const float* __restrict__ pnoise,
    const float* __restrict__ kinv,     // (64,64)
    float* __restrict__ out,            // [m_new (n,2048) | g (n,2048)]
    int n_total)
{
    const int n   = blockIdx.x;
    const int tid = threadIdx.x;

    __shared__ float Kl[1024];
    __shared__ float xl[8], yl[32];
    __shared__ float kfz[64], a_sh[64];
    __shared__ float t_sh[32], rc[32], rd[32], s1[32], s2[32];
    __shared__ float part[256];
    __shared__ float Bsh;

    for (int i = tid; i < 1024; i += 256) Kl[i] = Kmat[i];
    if (tid < 8)  xl[tid] = x[n * 8 + tid];
    if (tid < 32) yl[tid] = y[n * 32 + tid];
    const float var = pvar[0], ls = pls[0], nv = pnoise[0];
    __syncthreads();

    const float sc = 0.5f / (ls * ls);
    if (tid < 64) {
        float sq = 0.f;
#pragma unroll
        for (int d = 0; d < 8; ++d) {
            const float df = xl[d] - inducing[tid * 8 + d];
            sq += df * df;
        }
        kfz[tid] = var * expf(-sq * sc);
    }
    __syncthreads();

    if (tid < 64) {               // a = Kzz^-1 * kfz (symmetric: use columns)
        float acc = 0.f;
        for (int j = 0; j < 64; ++j) acc += kinv[j * 64 + tid] * kfz[j];
        a_sh[tid] = acc / var;    // kinv is (Kzz/var)^-1 ; A = Kzz^-1 kfz
    }
    __syncthreads();

    if (tid < 64) {               // wave 0: B = var - <kfz, a>
        float v = kfz[tid] * a_sh[tid];
        for (int off = 32; off; off >>= 1) v += __shfl_down(v, off);
        if (tid == 0) Bsh = var - v;
    }

    // gamma load + per-thread partial of t[j]
    const int   k8   = tid * 8;
    const int   jrow = tid >> 3;          // j = k/64, constant per thread
    const float4 g0 = *reinterpret_cast<const float4*>(gamma + (size_t)n * 2048 + k8);
    const float4 g1 = *reinterpret_cast<const float4*>(gamma + (size_t)n * 2048 + k8 + 4);
    float ga[8] = {g0.x, g0.y, g0.z, g0.w, g1.x, g1.y, g1.z, g1.w};

    float as[8];
    const int ab = (tid & 7) * 8;         // mm = (tid&7)*8 + e
#pragma unroll
    for (int e = 0; e < 8; ++e) as[e] = a_sh[ab + e];

    float pt = 0.f;
#pragma unroll
    for (int e = 0; e < 8; ++e) pt += as[e] * as[e] * ga[e];
    part[tid] = pt;
    __syncthreads();

    if (tid < 32) {
        float s = 0.f;
#pragma unroll
        for (int u = 0; u < 8; ++u) s += part[tid * 8 + u];
        t_sh[tid] = s;
    }
    __syncthreads();

    if (tid < 32) {                        // d, c per output dim i
        float acc = 0.f;
        for (int jj = 0; jj < 32; ++jj) {
            const float kv = Kl[tid * 32 + jj];
            acc += kv * kv * t_sh[jj];
        }
        const float ci = Bsh * Kl[tid * 33] + nv;
        const float di = acc + ci;
        rc[tid] = yl[tid] / ci;
        rd[tid] = 1.0f / di;
    }
    __syncthreads();

    if (tid < 32) {                        // s1, s2 per j
        float sa = 0.f, sb = 0.f;
        for (int i = 0; i < 32; ++i) {
            const float kv = Kl[i * 32 + tid];
            sa += kv * rc[i];
            sb += kv * kv * rd[i];
        }
        s1[tid] = sa;
        s2[tid] = sb;
    }
    __syncthreads();

    const float4 z0 = *reinterpret_cast<const float4*>(z + (size_t)n * 2048 + k8);
    const float4 z1 = *reinterpret_cast<const float4*>(z + (size_t)n * 2048 + k8 + 4);
    const float zv[8] = {z0.x, z0.y, z0.z, z0.w, z1.x, z1.y, z1.z, z1.w};

    const float s1j = s1[jrow], s2j = s2[jrow];
    float mn[8], gg[8];
#pragma unroll
    for (int e = 0; e < 8; ++e) {
        const float ge = ga[e];
        const float am = as[e];
        const float gm = ge * am;
        const float gv = ge - gm * gm * s2j;
        gg[e] = gv;
        mn[e] = gv * (zv[e] / ge + am * s1j);
    }

    float* o_m = out + (size_t)n * 2048 + k8;
    float* o_g = out + (size_t)n_total * 2048 + (size_t)n * 2048 + k8;
    *reinterpret_cast<float4*>(o_m)     = make_float4(mn[0], mn[1], mn[2], mn[3]);
    *reinterpret_cast<float4*>(o_m + 4) = make_float4(mn[4], mn[5], mn[6], mn[7]);
    *reinterpret_cast<float4*>(o_g)     = make_float4(gg[0], gg[1], gg[2], gg[3]);
    *reinterpret_cast<float4*>(o_g + 4) = make_float4(gg[4], gg[5], gg[6], gg[7]);
}

extern "C" void kernel_launch(void* const* d_in, const int* in_sizes, int n_in,
                              void* d_out, int out_size, void* d_ws, size_t ws_size,
                              hipStream_t stream)
{
    const float* x        = (const float*)d_in[0];
    const float* y        = (const float*)d_in[1];
    const float* z        = (const float*)d_in[2];
    const float* gamma    = (const float*)d_in[3];
    const float* inducing = (const float*)d_in[4];
    const float* Kmat     = (const float*)d_in[5];
    const float* pvar     = (const float*)d_in[6];
    const float* pls      = (const float*)d_in[7];
    const float* pnoise   = (const float*)d_in[8];
    float* out  = (float*)d_out;
    float* kinv = (float*)d_ws;          // 64*64*4 = 16 KB scratch

    const int n = in_sizes[0] / 8;       // 512

    kzz_invert_fast<<<dim3(1), dim3(1024), 0, stream>>>(inducing, pls, kinv);
    diag_sgp_kernel<<<dim3(n), dim3(256), 0, stream>>>(
        x, y, z, gamma, inducing, Kmat, pvar, pls, pnoise, kinv, out, n);
}

// Round 4
// 42.656 us; speedup vs baseline: 2.9507x; 1.1408x over previous
//
#include <hip/hip_runtime.h>

#define JITTER 1e-5f

// ---------------------------------------------------------------------------
// Kernel 1: register-resident Gauss-Jordan inversion of Kzz/var (64x64).
// 512 threads = 8 waves. Thread (r = tid&63, q = tid>>6) owns columns
// q*16..q*16+15 of row r of the augmented [Kzz | I] in 16 VGPRs.
// Panel-unrolled: outer runtime loop over 4 panels of 16 pivots, inner loop
// fully unrolled so every register index is compile-time static, but the
// total body stays ~5 KB (I-cache resident), unlike the round-3 full unroll.
// ONE barrier per step: pivot row is published UNSCALED together with the
// pivot column; every thread computes rinv itself. Double-buffered staging
// makes the single barrier race-free (reads of buf p finish before the
// barrier that precedes the next write of buf p).
// Same math/order as the round-3 verified kernel (absmax 4.9e-4).
// ---------------------------------------------------------------------------
__global__ __launch_bounds__(512) void kzz_invert_v2(
    const float* __restrict__ inducing,  // (64,8)
    const float* __restrict__ pls,
    float* __restrict__ inv_out)         // (64,64) = (Kzz/var)^-1
{
    const int tid = threadIdx.x;
    const int r = tid & 63;
    const int q = tid >> 6;              // 0..7, columns q*16 .. q*16+15

    __shared__ float Zt[8 * 64];                       // Zt[d][j]
    __shared__ __align__(16) float rowbuf[2][128];     // unscaled pivot row
    __shared__ float colbuf[2][64];                    // pivot column

    if (tid < 512) Zt[(tid & 7) * 64 + (tid >> 3)] = inducing[tid];
    const float ls = pls[0];
    const float sc = 0.5f / (ls * ls);
    __syncthreads();

    // init: left half (q<4) = Kzz/var = C + jitter*I ; right half = I
    float a[16];
    if (q < 4) {
#pragma unroll
        for (int j = 0; j < 16; ++j) {
            const int c = q * 16 + j;
            float sq = 0.f;
#pragma unroll
            for (int d = 0; d < 8; ++d) {
                const float df = Zt[d * 64 + r] - Zt[d * 64 + c];
                sq += df * df;
            }
            a[j] = expf(-sq * sc) + ((r == c) ? JITTER : 0.f);
        }
    } else {
#pragma unroll
        for (int j = 0; j < 16; ++j)
            a[j] = ((q - 4) * 16 + j == r) ? 1.f : 0.f;
    }

    for (int k0 = 0; k0 < 64; k0 += 16) {
        const int qk = k0 >> 4;                    // wave-uniform scalar
#pragma unroll
        for (int i = 0; i < 16; ++i) {
            const int k   = k0 + i;
            const int buf = i & 1;                 // == k&1 (k0 % 16 == 0)
            // ---- publish pivot column (pre-update) and UNSCALED pivot row
            if (q == qk) colbuf[buf][r] = a[i];    // static reg index ✓
            if (r == k) {
                *reinterpret_cast<float4*>(&rowbuf[buf][q * 16 + 0])  =
                    make_float4(a[0],  a[1],  a[2],  a[3]);
                *reinterpret_cast<float4*>(&rowbuf[buf][q * 16 + 4])  =
                    make_float4(a[4],  a[5],  a[6],  a[7]);
                *reinterpret_cast<float4*>(&rowbuf[buf][q * 16 + 8])  =
                    make_float4(a[8],  a[9],  a[10], a[11]);
                *reinterpret_cast<float4*>(&rowbuf[buf][q * 16 + 12]) =
                    make_float4(a[12], a[13], a[14], a[15]);
            }
            __syncthreads();                       // the ONLY barrier/step
            // ---- everyone: read pivot data (broadcast / 2-way = free)
            const float rinv = 1.0f / colbuf[buf][k];
            const float4 p0 = *reinterpret_cast<const float4*>(&rowbuf[buf][q * 16 + 0]);
            const float4 p1 = *reinterpret_cast<const float4*>(&rowbuf[buf][q * 16 + 4]);
            const float4 p2 = *reinterpret_cast<const float4*>(&rowbuf[buf][q * 16 + 8]);
            const float4 p3 = *reinterpret_cast<const float4*>(&rowbuf[buf][q * 16 + 12]);
            if (r == k) {                          // scale own row
                a[0]  = p0.x * rinv; a[1]  = p0.y * rinv; a[2]  = p0.z * rinv; a[3]  = p0.w * rinv;
                a[4]  = p1.x * rinv; a[5]  = p1.y * rinv; a[6]  = p1.z * rinv; a[7]  = p1.w * rinv;
                a[8]  = p2.x * rinv; a[9]  = p2.y * rinv; a[10] = p2.z * rinv; a[11] = p2.w * rinv;
                a[12] = p3.x * rinv; a[13] = p3.y * rinv; a[14] = p3.z * rinv; a[15] = p3.w * rinv;
            } else {                               // eliminate
                const float f = colbuf[buf][r] * rinv;
                a[0]  = fmaf(-f, p0.x, a[0]);  a[1]  = fmaf(-f, p0.y, a[1]);
                a[2]  = fmaf(-f, p0.z, a[2]);  a[3]  = fmaf(-f, p0.w, a[3]);
                a[4]  = fmaf(-f, p1.x, a[4]);  a[5]  = fmaf(-f, p1.y, a[5]);
                a[6]  = fmaf(-f, p1.z, a[6]);  a[7]  = fmaf(-f, p1.w, a[7]);
                a[8]  = fmaf(-f, p2.x, a[8]);  a[9]  = fmaf(-f, p2.y, a[9]);
                a[10] = fmaf(-f, p2.z, a[10]); a[11] = fmaf(-f, p2.w, a[11]);
                a[12] = fmaf(-f, p3.x, a[12]); a[13] = fmaf(-f, p3.y, a[13]);
                a[14] = fmaf(-f, p3.z, a[14]); a[15] = fmaf(-f, p3.w, a[15]);
            }
        }
    }

    if (q >= 4) {                         // right half now holds the inverse
        float* o = inv_out + r * 64 + (q - 4) * 16;
        *reinterpret_cast<float4*>(o)      = make_float4(a[0],  a[1],  a[2],  a[3]);
        *reinterpret_cast<float4*>(o + 4)  = make_float4(a[4],  a[5],  a[6],  a[7]);
        *reinterpret_cast<float4*>(o + 8)  = make_float4(a[8],  a[9],  a[10], a[11]);
        *reinterpret_cast<float4*>(o + 12) = make_float4(a[12], a[13], a[14], a[15]);
    }
}

// ---------------------------------------------------------------------------
// Kernel 2: one block per particle n (512 blocks x 256 threads).
// Round-1 verified math; changes: (a) gamma AND z prefetched at kernel
// entry, (b) a = kinv*kfz matvec parallelized over all 256 threads (4-way
// column split + LDS combine) instead of a 64-deep serial chain on 64
// threads, (c) Kl padded to pitch 33 (round-1 row reads were a 32-way bank
// conflict), (d) t-reduction via 8-lane shfl_xor tree (no LDS conflicts).
// ---------------------------------------------------------------------------
__global__ __launch_bounds__(256) void diag_sgp_kernel(
    const float* __restrict__ x,        // (n,8)
    const float* __restrict__ y,        // (n,32)
    const float* __restrict__ z,        // (n,2048)
    const float* __restrict__ gamma,    // (n,2048)
    const float* __restrict__ inducing, // (64,8)
    const float* __restrict__ Kmat,     // (32,32)
    const float* __restrict__ pvar,
    const float* __restrict__ pls,
    const float* __restrict__ pnoise,
    const float* __restrict__ kinv,     // (64,64) = (Kzz/var)^-1
    float* __restrict__ out,            // [m_new (n,2048) | g (n,2048)]
    int n_total)
{
    const int n   = blockIdx.x;
    const int tid = threadIdx.x;

    // ---- prefetch the HBM-heavy operands immediately ----
    const size_t base = (size_t)n * 2048 + tid * 8;
    const float4 g0 = *reinterpret_cast<const float4*>(gamma + base);
    const float4 g1 = *reinterpret_cast<const float4*>(gamma + base + 4);
    const float4 z0 = *reinterpret_cast<const float4*>(z + base);
    const float4 z1 = *reinterpret_cast<const float4*>(z + base + 4);

    __shared__ float Kl[32 * 33];                  // pitch 33: bank-safe rows
    __shared__ float xl[8], yl[32];
    __shared__ __align__(16) float kfz[64], a_sh[64];
    __shared__ float part2[4][64];
    __shared__ float t_sh[32], rc[32], rd[32], s1[32], s2[32];
    __shared__ float Bsh;

    for (int i = tid; i < 1024; i += 256)
        Kl[(i >> 5) * 33 + (i & 31)] = Kmat[i];
    if (tid < 8)  xl[tid] = x[n * 8 + tid];
    if (tid < 32) yl[tid] = y[n * 32 + tid];
    const float var = pvar[0], ls = pls[0], nv = pnoise[0];
    const float sc = 0.5f / (ls * ls);
    __syncthreads();                               // B1

    if (tid < 64) {
        float sq = 0.f;
#pragma unroll
        for (int d = 0; d < 8; ++d) {
            const float df = xl[d] - inducing[tid * 8 + d];
            sq += df * df;
        }
        kfz[tid] = var * expf(-sq * sc);
    }
    __syncthreads();                               // B2

    // ---- a = kinv * kfz, 4-way split over j (symmetric: column m reads) ----
    {
        const int m = tid & 63, h = tid >> 6;
        const float* kc = kinv + (h * 16) * 64 + m;
        float acc = 0.f;
#pragma unroll
        for (int j = 0; j < 16; ++j)
            acc += kc[j * 64] * kfz[h * 16 + j];
        part2[h][m] = acc;
    }
    __syncthreads();                               // B3

    if (tid < 64) {
        const float s = (part2[0][tid] + part2[1][tid] +
                         part2[2][tid] + part2[3][tid]) / var;
        a_sh[tid] = s;
        float v = kfz[tid] * s;                    // B = var - <kfz, a>
        for (int off = 32; off; off >>= 1) v += __shfl_down(v, off);
        if (tid == 0) Bsh = var - v;
    }
    __syncthreads();                               // B4

    // ---- t[j] = sum_mm a[mm]^2 gamma[j*64+mm] via 8-lane shfl tree ----
    const int jrow = tid >> 3;                     // j of this thread's 8 elems
    float ga[8] = {g0.x, g0.y, g0.z, g0.w, g1.x, g1.y, g1.z, g1.w};
    const int ab = (tid & 7) * 8;                  // mm = ab + e
    const float4 a0 = *reinterpret_cast<const float4*>(&a_sh[ab]);
    const float4 a1 = *reinterpret_cast<const float4*>(&a_sh[ab + 4]);
    const float as[8] = {a0.x, a0.y, a0.z, a0.w, a1.x, a1.y, a1.z, a1.w};

    float pt = 0.f;
#pragma unroll
    for (int e = 0; e < 8; ++e) pt += as[e] * as[e] * ga[e];
    pt += __shfl_xor(pt, 1);
    pt += __shfl_xor(pt, 2);
    pt += __shfl_xor(pt, 4);
    if ((tid & 7) == 0) t_sh[jrow] = pt;
    __syncthreads();                               // B5

    if (tid < 32) {                                // c, d per output dim i
        float acc = 0.f;
        for (int jj = 0; jj < 32; ++jj) {
            const float kv = Kl[tid * 33 + jj];
            acc += kv * kv * t_sh[jj];
        }
        const float ci = Bsh * Kl[tid * 34] + nv;  // diag: tid*33 + tid
        const float di = acc + ci;
        rc[tid] = yl[tid] / ci;
        rd[tid] = 1.0f / di;
    }
    __syncthreads();                               // B6

    if (tid < 32) {                                // s1, s2 per j
        float sa = 0.f, sb = 0.f;
        for (int i = 0; i < 32; ++i) {
            const float kv = Kl[i * 33 + tid];
            sa += kv * rc[i];
            sb += kv * kv * rd[i];
        }
        s1[tid] = sa;
        s2[tid] = sb;
    }
    __syncthreads();                               // B7

    // ---- outputs (z already in registers) ----
    const float zv[8] = {z0.x, z0.y, z0.z, z0.w, z1.x, z1.y, z1.z, z1.w};
    const float s1j = s1[jrow], s2j = s2[jrow];
    float mn[8], gg[8];
#pragma unroll
    for (int e = 0; e < 8; ++e) {
        const float ge = ga[e];
        const float am = as[e];
        const float gm = ge * am;
        const float gv = ge - gm * gm * s2j;
        gg[e] = gv;
        mn[e] = gv * (zv[e] / ge + am * s1j);
    }

    float* o_m = out + base;
    float* o_g = out + (size_t)n_total * 2048 + base;
    *reinterpret_cast<float4*>(o_m)     = make_float4(mn[0], mn[1], mn[2], mn[3]);
    *reinterpret_cast<float4*>(o_m + 4) = make_float4(mn[4], mn[5], mn[6], mn[7]);
    *reinterpret_cast<float4*>(o_g)     = make_float4(gg[0], gg[1], gg[2], gg[3]);
    *reinterpret_cast<float4*>(o_g + 4) = make_float4(gg[4], gg[5], gg[6], gg[7]);
}

extern "C" void kernel_launch(void* const* d_in, const int* in_sizes, int n_in,
                              void* d_out, int out_size, void* d_ws, size_t ws_size,
                              hipStream_t stream)
{
    const float* x        = (const float*)d_in[0];
    const float* y        = (const float*)d_in[1];
    const float* z        = (const float*)d_in[2];
    const float* gamma    = (const float*)d_in[3];
    const float* inducing = (const float*)d_in[4];
    const float* Kmat     = (const float*)d_in[5];
    const float* pvar     = (const float*)d_in[6];
    const float* pls      = (const float*)d_in[7];
    const float* pnoise   = (const float*)d_in[8];
    float* out  = (float*)d_out;
    float* kinv = (float*)d_ws;          // 64*64*4 = 16 KB scratch

    const int n = in_sizes[0] / 8;       // 512

    kzz_invert_v2<<<dim3(1), dim3(512), 0, stream>>>(inducing, pls, kinv);
    diag_sgp_kernel<<<dim3(n), dim3(256), 0, stream>>>(
        x, y, z, gamma, inducing, Kmat, pvar, pls, pnoise, kinv, out, n);
}

// Round 5
// 39.989 us; speedup vs baseline: 3.1475x; 1.0667x over previous
//
#include <hip/hip_runtime.h>

#define JITTER 1e-5f

// ---------------------------------------------------------------------------
// Single fused kernel: one block per particle (512 blocks x 256 threads,
// 2 blocks/CU). Each block:
//   1. prefetches its gamma/z rows (HBM latency hides under the solve)
//   2. builds C + jitter*I (64x64, var cancels) and e = exp(-||x-z||^2/2ls^2)
//   3. solves (C+jI) a = e by register-resident Gauss-Jordan on the
//      augmented system  -- SAME elimination order as the verified
//      round-1/3/4 inverse (absmax 4.9e-4), just applied to one RHS.
//      Thread (r = tid&63, q = tid>>6) owns cols q*16..q*16+15 of row r in
//      16 VGPRs; the RHS lives in a register of wave 0 (q==0), published
//      per step through a 1-word bbuf. One barrier per step, double-
//      buffered staging (race-free: step i+2's writes are 2 barriers after
//      step i's reads). q is wave-uniform -> all rowbuf reads broadcast.
//   4. B = var*(1 - <e,a>), then the verified epilogue (t, c, d, s1, s2,
//      m_new, g) with pitch-33 K and shfl-tree reductions.
// ---------------------------------------------------------------------------
__global__ __launch_bounds__(256) void diag_sgp_onekernel(
    const float* __restrict__ x,        // (n,8)
    const float* __restrict__ y,        // (n,32)
    const float* __restrict__ z,        // (n,2048)
    const float* __restrict__ gamma,    // (n,2048)
    const float* __restrict__ inducing, // (64,8)
    const float* __restrict__ Kmat,     // (32,32)
    const float* __restrict__ pvar,
    const float* __restrict__ pls,
    const float* __restrict__ pnoise,
    float* __restrict__ out,            // [m_new (n,2048) | g (n,2048)]
    int n_total)
{
    const int n   = blockIdx.x;
    const int tid = threadIdx.x;
    const int r   = tid & 63;            // row of the system
    const int q   = tid >> 6;            // wave id = column quarter (0..3)

    // ---- prefetch the HBM-heavy operands immediately ----
    const size_t base = (size_t)n * 2048 + tid * 8;
    const float4 g0 = *reinterpret_cast<const float4*>(gamma + base);
    const float4 g1 = *reinterpret_cast<const float4*>(gamma + base + 4);
    const float4 z0 = *reinterpret_cast<const float4*>(z + base);
    const float4 z1 = *reinterpret_cast<const float4*>(z + base + 4);

    __shared__ float Zt[8 * 64];                   // inducing transposed
    __shared__ float Kl[32 * 33];                  // K, pitch 33 (bank-safe)
    __shared__ float xl[8], yl[32];
    __shared__ float e_sh[64];                     // kfz / var
    __shared__ __align__(16) float a_sh[64];
    __shared__ __align__(16) float rowbuf[2][64];  // unscaled pivot row
    __shared__ float colbuf[2][64];                // pivot column
    __shared__ float bbuf[2];                      // unscaled pivot RHS
    __shared__ float t_sh[32], rc[32], rd[32], s1[32], s2[32];
    __shared__ float Bsh;

    for (int i = tid; i < 512; i += 256)
        Zt[(i & 7) * 64 + (i >> 3)] = inducing[i];
    for (int i = tid; i < 1024; i += 256)
        Kl[(i >> 5) * 33 + (i & 31)] = Kmat[i];
    if (tid < 8)  xl[tid] = x[n * 8 + tid];
    if (tid < 32) yl[tid] = y[n * 32 + tid];
    const float var = pvar[0], ls = pls[0], nv = pnoise[0];
    const float sc = 0.5f / (ls * ls);
    __syncthreads();                               // B1

    // ---- build matrix rows (16 regs/thread) and e ----
    float a[16];
#pragma unroll
    for (int j = 0; j < 16; ++j) {
        const int c = q * 16 + j;
        float sq = 0.f;
#pragma unroll
        for (int d = 0; d < 8; ++d) {
            const float df = Zt[d * 64 + r] - Zt[d * 64 + c];
            sq += df * df;
        }
        a[j] = __expf(-sq * sc) + ((r == c) ? JITTER : 0.f);
    }
    if (tid < 64) {
        float sq = 0.f;
#pragma unroll
        for (int d = 0; d < 8; ++d) {
            const float df = xl[d] - Zt[d * 64 + tid];
            sq += df * df;
        }
        e_sh[tid] = __expf(-sq * sc);
    }
    __syncthreads();                               // B2

    float b = (q == 0) ? e_sh[r] : 0.f;            // RHS lives on wave 0

    // ---- Gauss-Jordan on [M | b], one barrier per step ----
    for (int k0 = 0; k0 < 64; k0 += 16) {
        const int qk = k0 >> 4;                    // wave-uniform
#pragma unroll
        for (int i = 0; i < 16; ++i) {
            const int k   = k0 + i;
            const int buf = i & 1;
            if (q == qk) colbuf[buf][r] = a[i];    // static reg index
            if (r == k) {
                *reinterpret_cast<float4*>(&rowbuf[buf][q * 16 + 0])  =
                    make_float4(a[0],  a[1],  a[2],  a[3]);
                *reinterpret_cast<float4*>(&rowbuf[buf][q * 16 + 4])  =
                    make_float4(a[4],  a[5],  a[6],  a[7]);
                *reinterpret_cast<float4*>(&rowbuf[buf][q * 16 + 8])  =
                    make_float4(a[8],  a[9],  a[10], a[11]);
                *reinterpret_cast<float4*>(&rowbuf[buf][q * 16 + 12]) =
                    make_float4(a[12], a[13], a[14], a[15]);
                if (q == 0) bbuf[buf] = b;         // unscaled pivot RHS
            }
            __syncthreads();                       // the ONLY barrier/step
            const float rinv = 1.0f / colbuf[buf][k];          // broadcast
            const float4 p0 = *reinterpret_cast<const float4*>(&rowbuf[buf][q * 16 + 0]);
            const float4 p1 = *reinterpret_cast<const float4*>(&rowbuf[buf][q * 16 + 4]);
            const float4 p2 = *reinterpret_cast<const float4*>(&rowbuf[buf][q * 16 + 8]);
            const float4 p3 = *reinterpret_cast<const float4*>(&rowbuf[buf][q * 16 + 12]);
            if (r == k) {                          // scale own row + RHS
                a[0]  = p0.x * rinv; a[1]  = p0.y * rinv; a[2]  = p0.z * rinv; a[3]  = p0.w * rinv;
                a[4]  = p1.x * rinv; a[5]  = p1.y * rinv; a[6]  = p1.z * rinv; a[7]  = p1.w * rinv;
                a[8]  = p2.x * rinv; a[9]  = p2.y * rinv; a[10] = p2.z * rinv; a[11] = p2.w * rinv;
                a[12] = p3.x * rinv; a[13] = p3.y * rinv; a[14] = p3.z * rinv; a[15] = p3.w * rinv;
                b *= rinv;
            } else {                               // eliminate
                const float f = colbuf[buf][r] * rinv;   // 2-way alias: free
                a[0]  = fmaf(-f, p0.x, a[0]);  a[1]  = fmaf(-f, p0.y, a[1]);
                a[2]  = fmaf(-f, p0.z, a[2]);  a[3]  = fmaf(-f, p0.w, a[3]);
                a[4]  = fmaf(-f, p1.x, a[4]);  a[5]  = fmaf(-f, p1.y, a[5]);
                a[6]  = fmaf(-f, p1.z, a[6]);  a[7]  = fmaf(-f, p1.w, a[7]);
                a[8]  = fmaf(-f, p2.x, a[8]);  a[9]  = fmaf(-f, p2.y, a[9]);
                a[10] = fmaf(-f, p2.z, a[10]); a[11] = fmaf(-f, p2.w, a[11]);
                a[12] = fmaf(-f, p3.x, a[12]); a[13] = fmaf(-f, p3.y, a[13]);
                a[14] = fmaf(-f, p3.z, a[14]); a[15] = fmaf(-f, p3.w, a[15]);
                b = fmaf(-f, bbuf[buf], b);        // no-op for q!=0 (b=0)
            }
        }
    }
    if (q == 0) a_sh[r] = b;                       // a = (C+jI)^-1 e
    __syncthreads();                               // B3

    // ---- B = var*(1 - <e,a>)  (wave 0) ----
    if (tid < 64) {
        float v = e_sh[tid] * a_sh[tid];
        for (int off = 32; off; off >>= 1) v += __shfl_down(v, off);
        if (tid == 0) Bsh = var * (1.f - v);
    }

    // ---- t[j] = sum_mm a[mm]^2 gamma[j*64+mm] via 8-lane shfl tree ----
    const int jrow = tid >> 3;
    float ga[8] = {g0.x, g0.y, g0.z, g0.w, g1.x, g1.y, g1.z, g1.w};
    const int ab = (tid & 7) * 8;
    const float4 a0 = *reinterpret_cast<const float4*>(&a_sh[ab]);
    const float4 a1 = *reinterpret_cast<const float4*>(&a_sh[ab + 4]);
    const float as[8] = {a0.x, a0.y, a0.z, a0.w, a1.x, a1.y, a1.z, a1.w};

    float pt = 0.f;
#pragma unroll
    for (int e = 0; e < 8; ++e) pt += as[e] * as[e] * ga[e];
    pt += __shfl_xor(pt, 1);
    pt += __shfl_xor(pt, 2);
    pt += __shfl_xor(pt, 4);
    if ((tid & 7) == 0) t_sh[jrow] = pt;
    __syncthreads();                               // B4

    if (tid < 32) {                                // c, d per output dim i
        float acc = 0.f;
        for (int jj = 0; jj < 32; ++jj) {
            const float kv = Kl[tid * 33 + jj];
            acc += kv * kv * t_sh[jj];
        }
        const float ci = Bsh * Kl[tid * 34] + nv;  // diag entry
        const float di = acc + ci;
        rc[tid] = yl[tid] / ci;
        rd[tid] = 1.0f / di;
    }
    __syncthreads();                               // B5

    if (tid < 32) {                                // s1, s2 per j
        float sa = 0.f, sb = 0.f;
        for (int i = 0; i < 32; ++i) {
            const float kv = Kl[i * 33 + tid];
            sa += kv * rc[i];
            sb += kv * kv * rd[i];
        }
        s1[tid] = sa;
        s2[tid] = sb;
    }
    __syncthreads();                               // B6

    // ---- outputs (z already in registers) ----
    const float zv[8] = {z0.x, z0.y, z0.z, z0.w, z1.x, z1.y, z1.z, z1.w};
    const float s1j = s1[jrow], s2j = s2[jrow];
    float mn[8], gg[8];
#pragma unroll
    for (int e = 0; e < 8; ++e) {
        const float ge = ga[e];
        const float am = as[e];
        const float gm = ge * am;
        const float gv = ge - gm * gm * s2j;
        gg[e] = gv;
        mn[e] = gv * (zv[e] / ge + am * s1j);
    }

    float* o_m = out + base;
    float* o_g = out + (size_t)n_total * 2048 + base;
    *reinterpret_cast<float4*>(o_m)     = make_float4(mn[0], mn[1], mn[2], mn[3]);
    *reinterpret_cast<float4*>(o_m + 4) = make_float4(mn[4], mn[5], mn[6], mn[7]);
    *reinterpret_cast<float4*>(o_g)     = make_float4(gg[0], gg[1], gg[2], gg[3]);
    *reinterpret_cast<float4*>(o_g + 4) = make_float4(gg[4], gg[5], gg[6], gg[7]);
}

extern "C" void kernel_launch(void* const* d_in, const int* in_sizes, int n_in,
                              void* d_out, int out_size, void* d_ws, size_t ws_size,
                              hipStream_t stream)
{
    const float* x        = (const float*)d_in[0];
    const float* y        = (const float*)d_in[1];
    const float* z        = (const float*)d_in[2];
    const float* gamma    = (const float*)d_in[3];
    const float* inducing = (const float*)d_in[4];
    const float* Kmat     = (const float*)d_in[5];
    const float* pvar     = (const float*)d_in[6];
    const float* pls      = (const float*)d_in[7];
    const float* pnoise   = (const float*)d_in[8];
    float* out = (float*)d_out;

    const int n = in_sizes[0] / 8;       // 512

    diag_sgp_onekernel<<<dim3(n), dim3(256), 0, stream>>>(
        x, y, z, gamma, inducing, Kmat, pvar, pls, pnoise, out, n);
}

// Round 7
// 30.572 us; speedup vs baseline: 4.1170x; 1.3080x over previous
//
#include <hip/hip_runtime.h>

#define JITTER 1e-5f

__device__ __forceinline__ float rl(float v, int l) {
    return __uint_as_float(__builtin_amdgcn_readlane(__float_as_uint(v), l));
}

// ---------------------------------------------------------------------------
// One kernel, 256 blocks x 512 threads (2 particles/block).
// Wave 0 solves (C + jitter*I) a = e for BOTH particles with an all-register
// shuffle-only Gauss-Jordan, ROW-per-lane: lane r holds row[c] = M[r][c]
// (64 VGPRs) and the RHS b as a lane-local scalar. Fully unrolled, all
// register indices static. Per step k:
//   piv = readlane(row[k], k)            (M[k][k], uniform)
//   f   = row[k]                         (M[r][k], LANE-LOCAL -> no writelane)
//   fr  = (lane==k) ? 0 : f/piv          (pivot row defers its scaling)
//   row[c] -= fr * readlane(row[c], k)   for c in [k,64)  (cols<k already 0)
//   b      -= fr * readlane(b, k)
//   dg  = (lane==k) ? piv : dg
// final: a = b / dg.   Deferred-scaling GJ verified by hand on 2x2.
// No LDS, no barriers, no waitcnt in the chain -> pure VALU issue (~5.2k
// insts ~ 4 us). Epilogue = the round-5 verified code (absmax 4.9e-4).
// ---------------------------------------------------------------------------
__global__ __launch_bounds__(512) void diag_sgp_fused2(
    const float* __restrict__ x,        // (n,8)
    const float* __restrict__ y,        // (n,32)
    const float* __restrict__ z,        // (n,2048)
    const float* __restrict__ gamma,    // (n,2048)
    const float* __restrict__ inducing, // (64,8)
    const float* __restrict__ Kmat,     // (32,32)
    const float* __restrict__ pvar,
    const float* __restrict__ pls,
    const float* __restrict__ pnoise,
    float* __restrict__ out,            // [m_new (n,2048) | g (n,2048)]
    int n_total)
{
    const int tid = threadIdx.x;
    const int n0  = blockIdx.x * 2;
    const int t8  = tid & 255;           // thread within particle
    const int h   = tid >> 8;            // particle half (0/1)

    // ---- prefetch HBM-heavy operands immediately ----
    const size_t base = (size_t)(n0 + h) * 2048 + t8 * 8;
    const float4 g0 = *reinterpret_cast<const float4*>(gamma + base);
    const float4 g1 = *reinterpret_cast<const float4*>(gamma + base + 4);
    const float4 zv0 = *reinterpret_cast<const float4*>(z + base);
    const float4 zv1 = *reinterpret_cast<const float4*>(z + base + 4);

    __shared__ float Zt[8 * 64];                   // inducing transposed
    __shared__ float Kl[32 * 33];                  // K, pitch 33
    __shared__ float xl[2][8], yl[2][32];
    __shared__ float e_sh[2][64];
    __shared__ __align__(16) float a_sh[2][64];
    __shared__ float t_sh[2][32], rc[2][32], rd[2][32], s1s[2][32], s2s[2][32];
    __shared__ float Bsh[2];

    Zt[(tid & 7) * 64 + (tid >> 3)] = inducing[tid & 511];   // 512 elems
    for (int i = tid; i < 1024; i += 512)
        Kl[(i >> 5) * 33 + (i & 31)] = Kmat[i];
    if (tid < 16) xl[tid >> 3][tid & 7]  = x[n0 * 8 + tid];   // contiguous
    if (tid < 64) yl[tid >> 5][tid & 31] = y[n0 * 32 + tid];  // contiguous
    const float var = pvar[0], ls = pls[0], nv = pnoise[0];
    const float sc = 0.5f / (ls * ls);
    __syncthreads();                               // B1

    // ================= wave-0 register GJ solve (row-per-lane) ===========
    if (tid < 64) {
        const int lane = tid;
        float zc[8];
#pragma unroll
        for (int dd = 0; dd < 8; ++dd) zc[dd] = Zt[dd * 64 + lane];

        // build rows: row[c] = M[lane][c] = exp(-||z_lane - z_c||^2 sc) (+j)
        float row[64];
#pragma unroll
        for (int c = 0; c < 64; ++c) {
            float sq = 0.f;
#pragma unroll
            for (int dd = 0; dd < 8; ++dd) {
                const float df = zc[dd] - rl(zc[dd], c);
                sq = fmaf(df, df, sq);
            }
            const float v = __expf(-sq * sc);
            row[c] = (lane == c) ? v + JITTER : v;
        }
        // RHS (lane-local): b_r = exp(-||x - z_r||^2 sc), both particles
        float b0, b1;
        {
            float sq0 = 0.f, sq1 = 0.f;
#pragma unroll
            for (int dd = 0; dd < 8; ++dd) {
                const float d0 = xl[0][dd] - zc[dd]; sq0 = fmaf(d0, d0, sq0);
                const float d1 = xl[1][dd] - zc[dd]; sq1 = fmaf(d1, d1, sq1);
            }
            b0 = __expf(-sq0 * sc);
            b1 = __expf(-sq1 * sc);
        }
        e_sh[0][lane] = b0;
        e_sh[1][lane] = b1;

        float dg = 1.f;
#pragma unroll
        for (int k = 0; k < 64; ++k) {
            const float piv  = rl(row[k], k);      // M[k][k] (uniform)
            const float rinv = 1.0f / piv;
            const float f    = row[k];             // M[lane][k], lane-local
            const float fr   = (lane == k) ? 0.f : f * rinv;
#pragma unroll
            for (int c = k; c < 64; ++c) {         // cols < k are already 0
                const float s_c = rl(row[c], k);   // pivot row entry (SGPR)
                row[c] = fmaf(-fr, s_c, row[c]);
            }
            const float bk0 = rl(b0, k);
            const float bk1 = rl(b1, k);
            b0 = fmaf(-fr, bk0, b0);
            b1 = fmaf(-fr, bk1, b1);
            dg = (lane == k) ? piv : dg;
        }
        a_sh[0][lane] = b0 / dg;
        a_sh[1][lane] = b1 / dg;
    }
    __syncthreads();                               // B2

    // ================= verified epilogue, 2 particles =================
    if (t8 < 64) {                                 // waves 0 & 4: B reduce
        float v = e_sh[h][t8] * a_sh[h][t8];
        for (int off = 32; off; off >>= 1) v += __shfl_down(v, off);
        if (t8 == 0) Bsh[h] = var * (1.f - v);
    }

    // t[j] partials via 8-lane shfl tree
    const int jrow = t8 >> 3;
    float ga[8] = {g0.x, g0.y, g0.z, g0.w, g1.x, g1.y, g1.z, g1.w};
    const int ab = (t8 & 7) * 8;
    const float4 a0 = *reinterpret_cast<const float4*>(&a_sh[h][ab]);
    const float4 a1 = *reinterpret_cast<const float4*>(&a_sh[h][ab + 4]);
    const float as[8] = {a0.x, a0.y, a0.z, a0.w, a1.x, a1.y, a1.z, a1.w};

    float pt = 0.f;
#pragma unroll
    for (int e = 0; e < 8; ++e) pt += as[e] * as[e] * ga[e];
    pt += __shfl_xor(pt, 1);
    pt += __shfl_xor(pt, 2);
    pt += __shfl_xor(pt, 4);
    if ((t8 & 7) == 0) t_sh[h][jrow] = pt;
    __syncthreads();                               // B3

    if (t8 < 32) {                                 // c, d per output dim
        float acc = 0.f;
        for (int jj = 0; jj < 32; ++jj) {
            const float kv = Kl[t8 * 33 + jj];
            acc += kv * kv * t_sh[h][jj];
        }
        const float ci = Bsh[h] * Kl[t8 * 34] + nv;
        const float di = acc + ci;
        rc[h][t8] = yl[h][t8] / ci;
        rd[h][t8] = 1.0f / di;
    }
    __syncthreads();                               // B4

    if (t8 < 32) {                                 // s1, s2 per j
        float sa = 0.f, sb = 0.f;
        for (int i = 0; i < 32; ++i) {
            const float kv = Kl[i * 33 + t8];
            sa += kv * rc[h][i];
            sb += kv * kv * rd[h][i];
        }
        s1s[h][t8] = sa;
        s2s[h][t8] = sb;
    }
    __syncthreads();                               // B5

    const float zv[8] = {zv0.x, zv0.y, zv0.z, zv0.w, zv1.x, zv1.y, zv1.z, zv1.w};
    const float s1j = s1s[h][jrow], s2j = s2s[h][jrow];
    float mn[8], gg[8];
#pragma unroll
    for (int e = 0; e < 8; ++e) {
        const float ge = ga[e];
        const float am = as[e];
        const float gm = ge * am;
        const float gv = ge - gm * gm * s2j;
        gg[e] = gv;
        mn[e] = gv * (zv[e] / ge + am * s1j);
    }

    float* o_m = out + base;
    float* o_g = out + (size_t)n_total * 2048 + base;
    *reinterpret_cast<float4*>(o_m)     = make_float4(mn[0], mn[1], mn[2], mn[3]);
    *reinterpret_cast<float4*>(o_m + 4) = make_float4(mn[4], mn[5], mn[6], mn[7]);
    *reinterpret_cast<float4*>(o_g)     = make_float4(gg[0], gg[1], gg[2], gg[3]);
    *reinterpret_cast<float4*>(o_g + 4) = make_float4(gg[4], gg[5], gg[6], gg[7]);
}

extern "C" void kernel_launch(void* const* d_in, const int* in_sizes, int n_in,
                              void* d_out, int out_size, void* d_ws, size_t ws_size,
                              hipStream_t stream)
{
    const float* x        = (const float*)d_in[0];
    const float* y        = (const float*)d_in[1];
    const float* z        = (const float*)d_in[2];
    const float* gamma    = (const float*)d_in[3];
    const float* inducing = (const float*)d_in[4];
    const float* Kmat     = (const float*)d_in[5];
    const float* pvar     = (const float*)d_in[6];
    const float* pls      = (const float*)d_in[7];
    const float* pnoise   = (const float*)d_in[8];
    float* out = (float*)d_out;

    const int n = in_sizes[0] / 8;       // 512
    diag_sgp_fused2<<<dim3(n / 2), dim3(512), 0, stream>>>(
        x, y, z, gamma, inducing, Kmat, pvar, pls, pnoise, out, n);
}